// Round 6
// baseline (762.915 us; speedup 1.0000x reference)
//
#include <hip/hip_runtime.h>
#include <hip/hip_bf16.h>

// Problem constants (from reference): B=262144, D=256, S=16, C=10.
#define D_DIM 256
#define S_SYS 16
#define C_CLS 10
#define SPB   256   // bucket padding granule = block size -> every BLOCK single-system

// Workspace layout (ints):
//   [0   .. 255]  hist    (16 bins, 64B-strided: hist[t*16])
//   [256 .. 511]  cursor  (scatter-mutated)
//   [512 .. 767]  pstart  (immutable padded starts)
//   [768]         ntot    (padded total)
//   byte 4096+    idx     (sorted packed entries: i | s<<28; sentinel 0xFFFFFFFF)
#define WS_HIST   0
#define WS_CURSOR 256
#define WS_PSTART 512
#define WS_NTOT   768
#define WS_IDX_BYTES 4096

__global__ void init_k(int* __restrict__ ws) {
    if (threadIdx.x < 512) ws[threadIdx.x] = 0;
}

__global__ __launch_bounds__(256) void hist_k(const int* __restrict__ sid, int n,
                                              int* __restrict__ hist) {
    __shared__ int lh[S_SYS];
    if (threadIdx.x < S_SYS) lh[threadIdx.x] = 0;
    __syncthreads();
    int i = blockIdx.x * 256 + threadIdx.x;
    if (i < n) atomicAdd(&lh[sid[i]], 1);
    __syncthreads();
    if (threadIdx.x < S_SYS) {
        int c = lh[threadIdx.x];
        if (c) atomicAdd(&hist[threadIdx.x * 16], c);
    }
}

__global__ void scan_k(int* __restrict__ ws) {
    if (threadIdx.x == 0 && blockIdx.x == 0) {
        int acc = 0;
        for (int t = 0; t < S_SYS; ++t) {
            ws[WS_CURSOR + t * 16] = acc;
            ws[WS_PSTART + t * 16] = acc;
            int c = ws[WS_HIST + t * 16];
            acc += ((c + SPB - 1) / SPB) * SPB;
        }
        ws[WS_NTOT] = acc;
    }
}

// sentinel-fill ONLY bucket gaps (< 16*255 entries total)
__global__ void pad_k(const int* __restrict__ ws, unsigned* __restrict__ idx) {
    int t = blockIdx.x;
    int base = ws[WS_PSTART + t * 16];
    int cnt  = ws[WS_HIST + t * 16];
    int pcnt = ((cnt + SPB - 1) / SPB) * SPB;
    for (int u = cnt + threadIdx.x; u < pcnt; u += blockDim.x)
        idx[base + u] = 0xFFFFFFFFu;
}

__global__ __launch_bounds__(256) void scatter_k(const int* __restrict__ sid, int n,
                                                 int* __restrict__ cursor,
                                                 unsigned* __restrict__ idx) {
    __shared__ int wcnt[4][S_SYS];
    __shared__ int bbase[S_SYS];
    int i = blockIdx.x * 256 + threadIdx.x;
    int w = threadIdx.x >> 6;
    int lane = threadIdx.x & 63;
    int s = (i < n) ? sid[i] : -1;

    unsigned long long mym = 0;
    #pragma unroll 1
    for (int t = 0; t < S_SYS; ++t) {
        unsigned long long m = __ballot(s == t);
        if (lane == 0) wcnt[w][t] = (int)__popcll(m);
        if (s == t) mym = m;
    }
    int rank = (int)__popcll(mym & ((1ull << lane) - 1ull));
    __syncthreads();
    if (threadIdx.x < S_SYS) {
        int t = threadIdx.x, acc = 0;
        #pragma unroll
        for (int ww = 0; ww < 4; ++ww) { int c = wcnt[ww][t]; wcnt[ww][t] = acc; acc += c; }
        bbase[t] = atomicAdd(&cursor[t * 16], acc);
    }
    __syncthreads();
    if (i < n) {
        int pos = bbase[s] + wcnt[w][s] + rank;
        idx[pos] = (unsigned)i | ((unsigned)s << 28);
    }
}

// ---------------- main v4: thread-per-sample, W in LDS (lgkm-decoupled) ----
// SPB=256 -> every block is single-system. Block stages W[s] (10KB) + b[s]
// into LDS once, syncs, then each lane processes one sample:
//  - x row read as 8 chunks of 8 consecutive float4 (one 128B line/lane/chunk,
//    MSHR-merged), double-buffered xa/xq -> vmcnt queue carries ONLY x.
//  - W from LDS: same-address across 64 lanes -> broadcast, conflict-free,
//    counted by lgkmcnt -> cannot force a vmcnt drain (the round-3 flaw: W as
//    global_load shares the in-order vmcnt queue and defeats the prefetch).
__global__ __launch_bounds__(256, 4) void main4_k(const float* __restrict__ x,
                                                  const float* __restrict__ W,
                                                  const float* __restrict__ b,
                                                  const int* __restrict__ ws,
                                                  const unsigned* __restrict__ idx,
                                                  float* __restrict__ out) {
    __shared__ float4 Wl[C_CLS * D_DIM / 4];   // 640 float4 = 10 KB
    __shared__ float  bl[C_CLS];
    const int tid = threadIdx.x;
    const long bpos = (long)blockIdx.x * SPB;
    if (bpos >= (long)ws[WS_NTOT]) return;     // whole block exits (uniform) - no sync hazard

    const unsigned e  = idx[bpos + tid];       // this thread's sample slot
    const unsigned e0 = idx[bpos];             // first slot of a live block is always real
    const int s = __builtin_amdgcn_readfirstlane((int)(e0 >> 28)) & (S_SYS - 1);
    const bool live = (e != 0xFFFFFFFFu);
    const int irow = live ? (int)(e & 0x0FFFFFFFu) : 0;

    // stage W[s] + b[s] into LDS (coalesced: 256 threads x <=3 float4)
    const float4* __restrict__ Wg = (const float4*)W + (size_t)s * (C_CLS * D_DIM / 4);
    #pragma unroll
    for (int t = 0; t < 3; ++t) {
        int u = tid + t * 256;
        if (u < C_CLS * D_DIM / 4) Wl[u] = Wg[u];
    }
    if (tid < C_CLS) bl[tid] = b[s * C_CLS + tid];
    __syncthreads();

    const float4* __restrict__ xr = (const float4*)x + (size_t)irow * (D_DIM / 4);

    float acc[C_CLS];
    #pragma unroll
    for (int c = 0; c < C_CLS; ++c) acc[c] = bl[c];

    float4 xa[8], xq[8];
    #pragma unroll
    for (int j = 0; j < 8; ++j) xa[j] = xr[j];       // chunk 0 = line 0

    #pragma unroll 1
    for (int ch = 0; ch < 8; ch += 2) {
        // prefetch chunk ch+1 (next 128B line) into xq
        #pragma unroll
        for (int j = 0; j < 8; ++j) xq[j] = xr[(ch + 1) * 8 + j];
        // compute chunk ch from xa; W via LDS broadcast (lgkmcnt)
        #pragma unroll
        for (int c = 0; c < C_CLS; ++c) {
            #pragma unroll
            for (int j = 0; j < 8; ++j) {
                const float4 wv = Wl[c * (D_DIM / 4) + ch * 8 + j];
                acc[c] = fmaf(xa[j].x, wv.x,
                          fmaf(xa[j].y, wv.y,
                           fmaf(xa[j].z, wv.z,
                            fmaf(xa[j].w, wv.w, acc[c]))));
            }
        }
        // prefetch chunk ch+2 into xa
        if (ch + 2 < 8) {
            #pragma unroll
            for (int j = 0; j < 8; ++j) xa[j] = xr[(ch + 2) * 8 + j];
        }
        // compute chunk ch+1 from xq
        #pragma unroll
        for (int c = 0; c < C_CLS; ++c) {
            #pragma unroll
            for (int j = 0; j < 8; ++j) {
                const float4 wv = Wl[c * (D_DIM / 4) + (ch + 1) * 8 + j];
                acc[c] = fmaf(xq[j].x, wv.x,
                          fmaf(xq[j].y, wv.y,
                           fmaf(xq[j].z, wv.z,
                            fmaf(xq[j].w, wv.w, acc[c]))));
            }
        }
    }

    if (live) {
        // 40B rows are 8B-aligned -> 5x float2 stores
        float2* op = (float2*)(out + (size_t)irow * C_CLS);
        #pragma unroll
        for (int t = 0; t < 5; ++t) op[t] = make_float2(acc[2 * t], acc[2 * t + 1]);
    }
}

// ---------------- fallback (workspace too small): thread-per-sample ----------------
__global__ __launch_bounds__(256) void fallback_k(const float* __restrict__ x,
                                                  const int* __restrict__ sid,
                                                  const float* __restrict__ W,
                                                  const float* __restrict__ b,
                                                  float* __restrict__ out, int n) {
    int i = blockIdx.x * 256 + threadIdx.x;
    if (i >= n) return;
    int s = sid[i];
    const float4* xr = (const float4*)(x) + (size_t)i * (D_DIM / 4);
    const float4* wr = (const float4*)(W) + (size_t)s * (C_CLS * D_DIM / 4);
    float acc[C_CLS];
    #pragma unroll
    for (int c = 0; c < C_CLS; ++c) acc[c] = 0.f;
    for (int k = 0; k < D_DIM / 4; ++k) {
        float4 xv = xr[k];
        #pragma unroll
        for (int c = 0; c < C_CLS; ++c) {
            float4 wv = wr[c * (D_DIM / 4) + k];
            acc[c] = fmaf(xv.x, wv.x, fmaf(xv.y, wv.y, fmaf(xv.z, wv.z, fmaf(xv.w, wv.w, acc[c]))));
        }
    }
    #pragma unroll
    for (int c = 0; c < C_CLS; ++c) out[(size_t)i * C_CLS + c] = acc[c] + b[s * C_CLS + c];
}

extern "C" void kernel_launch(void* const* d_in, const int* in_sizes, int n_in,
                              void* d_out, int out_size, void* d_ws, size_t ws_size,
                              hipStream_t stream) {
    const float* x = (const float*)d_in[0];
    const int* sid = (const int*)d_in[1];
    const float* W = (const float*)d_in[2];
    const float* b = (const float*)d_in[3];
    float* out = (float*)d_out;
    const int n = in_sizes[1];   // B

    const size_t idx_entries = (size_t)n + S_SYS * (SPB - 1);   // padded upper bound
    const size_t ws_needed = WS_IDX_BYTES + idx_entries * sizeof(unsigned);

    if (ws_size < ws_needed) {
        fallback_k<<<(n + 255) / 256, 256, 0, stream>>>(x, sid, W, b, out, n);
        return;
    }

    int* ws = (int*)d_ws;
    unsigned* idx = (unsigned*)((char*)d_ws + WS_IDX_BYTES);

    const int blocks256 = (n + 255) / 256;
    init_k<<<1, 512, 0, stream>>>(ws);
    hist_k<<<blocks256, 256, 0, stream>>>(sid, n, ws + WS_HIST);
    scan_k<<<1, 64, 0, stream>>>(ws);
    pad_k<<<S_SYS, 256, 0, stream>>>(ws, idx);
    scatter_k<<<blocks256, 256, 0, stream>>>(sid, n, ws + WS_CURSOR, idx);

    const int nblk_main = (int)((idx_entries + SPB - 1) / SPB) + 1;  // fixed upper bound
    main4_k<<<nblk_main, 256, 0, stream>>>(x, W, b, ws, idx, out);
}

// Round 7
// 138.389 us; speedup vs baseline: 5.5128x; 5.5128x over previous
//
#include <hip/hip_runtime.h>
#include <hip/hip_bf16.h>

// Problem constants (from reference): B=262144, D=256, S=16, C=10.
#define D_DIM 256
#define S_SYS 16
#define C_CLS 10
#define SPB   256   // bucket padding granule = block size -> every BLOCK single-system

// Workspace layout (ints):
//   [0   .. 255]  hist    (16 bins, 64B-strided: hist[t*16])
//   [256 .. 511]  cursor  (scatter-mutated)
//   [512 .. 767]  pstart  (immutable padded starts)
//   [768]         ntot    (padded total)
//   byte 4096+    idx     (sorted packed entries: i | s<<28; sentinel 0xFFFFFFFF)
#define WS_HIST   0
#define WS_CURSOR 256
#define WS_PSTART 512
#define WS_NTOT   768
#define WS_IDX_BYTES 4096

__global__ void init_k(int* __restrict__ ws) {
    if (threadIdx.x < 512) ws[threadIdx.x] = 0;
}

__global__ __launch_bounds__(256) void hist_k(const int* __restrict__ sid, int n,
                                              int* __restrict__ hist) {
    __shared__ int lh[S_SYS];
    if (threadIdx.x < S_SYS) lh[threadIdx.x] = 0;
    __syncthreads();
    int i = blockIdx.x * 256 + threadIdx.x;
    if (i < n) atomicAdd(&lh[sid[i]], 1);
    __syncthreads();
    if (threadIdx.x < S_SYS) {
        int c = lh[threadIdx.x];
        if (c) atomicAdd(&hist[threadIdx.x * 16], c);
    }
}

__global__ void scan_k(int* __restrict__ ws) {
    if (threadIdx.x == 0 && blockIdx.x == 0) {
        int acc = 0;
        for (int t = 0; t < S_SYS; ++t) {
            ws[WS_CURSOR + t * 16] = acc;
            ws[WS_PSTART + t * 16] = acc;
            int c = ws[WS_HIST + t * 16];
            acc += ((c + SPB - 1) / SPB) * SPB;
        }
        ws[WS_NTOT] = acc;
    }
}

// sentinel-fill ONLY bucket gaps (< 16*255 entries total)
__global__ void pad_k(const int* __restrict__ ws, unsigned* __restrict__ idx) {
    int t = blockIdx.x;
    int base = ws[WS_PSTART + t * 16];
    int cnt  = ws[WS_HIST + t * 16];
    int pcnt = ((cnt + SPB - 1) / SPB) * SPB;
    for (int u = cnt + threadIdx.x; u < pcnt; u += blockDim.x)
        idx[base + u] = 0xFFFFFFFFu;
}

__global__ __launch_bounds__(256) void scatter_k(const int* __restrict__ sid, int n,
                                                 int* __restrict__ cursor,
                                                 unsigned* __restrict__ idx) {
    __shared__ int wcnt[4][S_SYS];
    __shared__ int bbase[S_SYS];
    int i = blockIdx.x * 256 + threadIdx.x;
    int w = threadIdx.x >> 6;
    int lane = threadIdx.x & 63;
    int s = (i < n) ? sid[i] : -1;

    unsigned long long mym = 0;
    #pragma unroll 1
    for (int t = 0; t < S_SYS; ++t) {
        unsigned long long m = __ballot(s == t);
        if (lane == 0) wcnt[w][t] = (int)__popcll(m);
        if (s == t) mym = m;
    }
    int rank = (int)__popcll(mym & ((1ull << lane) - 1ull));
    __syncthreads();
    if (threadIdx.x < S_SYS) {
        int t = threadIdx.x, acc = 0;
        #pragma unroll
        for (int ww = 0; ww < 4; ++ww) { int c = wcnt[ww][t]; wcnt[ww][t] = acc; acc += c; }
        bbase[t] = atomicAdd(&cursor[t * 16], acc);
    }
    __syncthreads();
    if (i < n) {
        int pos = bbase[s] + wcnt[w][s] + rank;
        idx[pos] = (unsigned)i | ((unsigned)s << 28);
    }
}

// ---------------- main v4b: thread-per-sample, W in LDS, NO occupancy cap ----
// Round-6 lesson: __launch_bounds__(256,4) forced VGPR<=64 -> xa/xq spilled to
// scratch -> 1.36 GB of spill traffic, 731 us. This kernel needs ~110 VGPR;
// let the allocator have them (4 waves/SIMD occupancy is plenty).
//  - SPB=256 -> every block single-system; W[s]+b[s] staged once in LDS.
//  - x row read as 8 chunks of 8 consecutive float4 (one 128B line/lane/chunk),
//    double-buffered xa/xq -> vmcnt queue carries ONLY x.
//  - W from LDS: same-address broadcast across lanes, conflict-free, lgkmcnt.
__global__ __launch_bounds__(256) void main4_k(const float* __restrict__ x,
                                               const float* __restrict__ W,
                                               const float* __restrict__ b,
                                               const int* __restrict__ ws,
                                               const unsigned* __restrict__ idx,
                                               float* __restrict__ out) {
    __shared__ float4 Wl[C_CLS * D_DIM / 4];   // 640 float4 = 10 KB
    __shared__ float  bl[C_CLS];
    const int tid = threadIdx.x;
    const long bpos = (long)blockIdx.x * SPB;
    if (bpos >= (long)ws[WS_NTOT]) return;     // whole block exits (uniform) - no sync hazard

    const unsigned e  = idx[bpos + tid];       // this thread's sample slot
    const unsigned e0 = idx[bpos];             // first slot of a live block is always real
    const int s = __builtin_amdgcn_readfirstlane((int)(e0 >> 28)) & (S_SYS - 1);
    const bool live = (e != 0xFFFFFFFFu);
    const int irow = live ? (int)(e & 0x0FFFFFFFu) : 0;

    // stage W[s] + b[s] into LDS (coalesced: 256 threads x <=3 float4)
    const float4* __restrict__ Wg = (const float4*)W + (size_t)s * (C_CLS * D_DIM / 4);
    #pragma unroll
    for (int t = 0; t < 3; ++t) {
        int u = tid + t * 256;
        if (u < C_CLS * D_DIM / 4) Wl[u] = Wg[u];
    }
    if (tid < C_CLS) bl[tid] = b[s * C_CLS + tid];
    __syncthreads();

    const float4* __restrict__ xr = (const float4*)x + (size_t)irow * (D_DIM / 4);

    float acc[C_CLS];
    #pragma unroll
    for (int c = 0; c < C_CLS; ++c) acc[c] = bl[c];

    float4 xa[8], xq[8];
    #pragma unroll
    for (int j = 0; j < 8; ++j) xa[j] = xr[j];       // chunk 0 = line 0

    #pragma unroll 1
    for (int ch = 0; ch < 8; ch += 2) {
        // prefetch chunk ch+1 (next 128B line) into xq
        #pragma unroll
        for (int j = 0; j < 8; ++j) xq[j] = xr[(ch + 1) * 8 + j];
        // compute chunk ch from xa; W via LDS broadcast (lgkmcnt)
        #pragma unroll
        for (int c = 0; c < C_CLS; ++c) {
            #pragma unroll
            for (int j = 0; j < 8; ++j) {
                const float4 wv = Wl[c * (D_DIM / 4) + ch * 8 + j];
                acc[c] = fmaf(xa[j].x, wv.x,
                          fmaf(xa[j].y, wv.y,
                           fmaf(xa[j].z, wv.z,
                            fmaf(xa[j].w, wv.w, acc[c]))));
            }
        }
        // prefetch chunk ch+2 into xa
        if (ch + 2 < 8) {
            #pragma unroll
            for (int j = 0; j < 8; ++j) xa[j] = xr[(ch + 2) * 8 + j];
        }
        // compute chunk ch+1 from xq
        #pragma unroll
        for (int c = 0; c < C_CLS; ++c) {
            #pragma unroll
            for (int j = 0; j < 8; ++j) {
                const float4 wv = Wl[c * (D_DIM / 4) + (ch + 1) * 8 + j];
                acc[c] = fmaf(xq[j].x, wv.x,
                          fmaf(xq[j].y, wv.y,
                           fmaf(xq[j].z, wv.z,
                            fmaf(xq[j].w, wv.w, acc[c]))));
            }
        }
    }

    if (live) {
        // 40B rows are 8B-aligned -> 5x float2 stores
        float2* op = (float2*)(out + (size_t)irow * C_CLS);
        #pragma unroll
        for (int t = 0; t < 5; ++t) op[t] = make_float2(acc[2 * t], acc[2 * t + 1]);
    }
}

// ---------------- fallback (workspace too small): thread-per-sample ----------------
__global__ __launch_bounds__(256) void fallback_k(const float* __restrict__ x,
                                                  const int* __restrict__ sid,
                                                  const float* __restrict__ W,
                                                  const float* __restrict__ b,
                                                  float* __restrict__ out, int n) {
    int i = blockIdx.x * 256 + threadIdx.x;
    if (i >= n) return;
    int s = sid[i];
    const float4* xr = (const float4*)(x) + (size_t)i * (D_DIM / 4);
    const float4* wr = (const float4*)(W) + (size_t)s * (C_CLS * D_DIM / 4);
    float acc[C_CLS];
    #pragma unroll
    for (int c = 0; c < C_CLS; ++c) acc[c] = 0.f;
    for (int k = 0; k < D_DIM / 4; ++k) {
        float4 xv = xr[k];
        #pragma unroll
        for (int c = 0; c < C_CLS; ++c) {
            float4 wv = wr[c * (D_DIM / 4) + k];
            acc[c] = fmaf(xv.x, wv.x, fmaf(xv.y, wv.y, fmaf(xv.z, wv.z, fmaf(xv.w, wv.w, acc[c]))));
        }
    }
    #pragma unroll
    for (int c = 0; c < C_CLS; ++c) out[(size_t)i * C_CLS + c] = acc[c] + b[s * C_CLS + c];
}

extern "C" void kernel_launch(void* const* d_in, const int* in_sizes, int n_in,
                              void* d_out, int out_size, void* d_ws, size_t ws_size,
                              hipStream_t stream) {
    const float* x = (const float*)d_in[0];
    const int* sid = (const int*)d_in[1];
    const float* W = (const float*)d_in[2];
    const float* b = (const float*)d_in[3];
    float* out = (float*)d_out;
    const int n = in_sizes[1];   // B

    const size_t idx_entries = (size_t)n + S_SYS * (SPB - 1);   // padded upper bound
    const size_t ws_needed = WS_IDX_BYTES + idx_entries * sizeof(unsigned);

    if (ws_size < ws_needed) {
        fallback_k<<<(n + 255) / 256, 256, 0, stream>>>(x, sid, W, b, out, n);
        return;
    }

    int* ws = (int*)d_ws;
    unsigned* idx = (unsigned*)((char*)d_ws + WS_IDX_BYTES);

    const int blocks256 = (n + 255) / 256;
    init_k<<<1, 512, 0, stream>>>(ws);
    hist_k<<<blocks256, 256, 0, stream>>>(sid, n, ws + WS_HIST);
    scan_k<<<1, 64, 0, stream>>>(ws);
    pad_k<<<S_SYS, 256, 0, stream>>>(ws, idx);
    scatter_k<<<blocks256, 256, 0, stream>>>(sid, n, ws + WS_CURSOR, idx);

    const int nblk_main = (int)((idx_entries + SPB - 1) / SPB) + 1;  // fixed upper bound
    main4_k<<<nblk_main, 256, 0, stream>>>(x, W, b, ws, idx, out);
}

// Round 8
// 69.580 us; speedup vs baseline: 10.9645x; 1.9889x over previous
//
#include <hip/hip_runtime.h>
#include <hip/hip_bf16.h>

// Problem constants (from reference): B=262144, D=256, S=16, C=10.
#define D_DIM 256
#define S_SYS 16
#define C_CLS 10
#define BLK   1024                 // 16 waves/block
#define GRID  256                  // 1 block per CU (82KB LDS -> 1 block/CU anyway)
#define CPB   128                  // samples per chunk (1024 threads / 8 lanes-per-sample)
#define WSTR  1282                 // u32 stride per system: 1280 pairs + 2 pad
                                   // (even -> 8B-aligned uint2 reads; %32==2 -> distinct
                                   //  bank offset 2s per system; same-sid lanes broadcast)

// No sort, no workspace, single kernel:
//  - x streamed in NATURAL order: 8-lane group per sample; load instr j covers
//    8 consecutive rows x 128B fully-consumed contiguous lines (optimal L1+DRAM).
//  - All 16 systems' W staged once per block into LDS as packed bf16 pairs
//    (82KB); per-lane sid-divergent reads are uint2 ds_read_b64, <=2-way-ish
//    conflicts via the stride pad (2-way is free, m136).
//  - 2-deep chunk pipeline with two static float4[8] buffers (no runtime
//    indexing -> stays in registers).

__device__ __forceinline__ void load_x(float4 xb[8], const float* __restrict__ x,
                                       long i, int n, int q) {
    const long r = (i < n) ? i : (long)(n - 1);           // clamp (store is masked)
    const float4* p = (const float4*)(x + r * D_DIM) + q; // d = j*32 + q*4
    #pragma unroll
    for (int j = 0; j < 8; ++j) xb[j] = p[j * 8];
}

__device__ __forceinline__ void step_compute(const float4 xb[8], long i, int n, int q,
                                             const unsigned* __restrict__ Wl,
                                             const float* __restrict__ bl,
                                             const int* __restrict__ sid,
                                             float* __restrict__ out) {
    const bool live = (i < n);
    const int s = sid[live ? i : 0] & (S_SYS - 1);
    const unsigned* wp = Wl + (unsigned)s * WSTR;
    const int q2 = q * 2;

    float acc[C_CLS];
    #pragma unroll
    for (int c = 0; c < C_CLS; ++c) acc[c] = 0.f;

    #pragma unroll
    for (int j = 0; j < 8; ++j) {
        const float4 xv = xb[j];
        #pragma unroll
        for (int c = 0; c < C_CLS; ++c) {
            // W[s][c][j*32 + q*4 .. +3] as 2 packed-bf16 u32s (8B, ds_read_b64)
            const uint2 w2 = *(const uint2*)&wp[c * 128 + j * 16 + q2];
            const float w0 = __uint_as_float(w2.x << 16);
            const float w1 = __uint_as_float(w2.x & 0xFFFF0000u);
            const float w2f = __uint_as_float(w2.y << 16);
            const float w3 = __uint_as_float(w2.y & 0xFFFF0000u);
            acc[c] = fmaf(xv.x, w0,
                      fmaf(xv.y, w1,
                       fmaf(xv.z, w2f,
                        fmaf(xv.w, w3, acc[c]))));
        }
    }

    // all-reduce each class within the 8-lane group (xor 1,2,4 stay in-group)
    float v0 = 0.f, v1 = 0.f;
    #pragma unroll
    for (int c = 0; c < C_CLS; ++c) {
        float r = acc[c];
        r += __shfl_xor(r, 1);
        r += __shfl_xor(r, 2);
        r += __shfl_xor(r, 4);
        if (c == q)     v0 = r;   // compile-time c, runtime compare (no scratch)
        if (c == 8 + q) v1 = r;
    }
    if (live) {
        float* op = out + i * C_CLS;
        op[q] = v0 + bl[s * C_CLS + q];
        if (q < 2) op[8 + q] = v1 + bl[s * C_CLS + 8 + q];
    }
}

__global__ __launch_bounds__(BLK) void mainf_k(const float* __restrict__ x,
                                               const int* __restrict__ sid,
                                               const float* __restrict__ W,
                                               const float* __restrict__ b,
                                               float* __restrict__ out, int n) {
    __shared__ unsigned Wl[S_SYS * WSTR];     // 82,048 B
    __shared__ float    bl[S_SYS * C_CLS];    // 640 B

    const int tid = threadIdx.x;
    const int nch = (n + CPB - 1) / CPB;
    const int cpb = (nch + (int)gridDim.x - 1) / (int)gridDim.x;  // chunks per block
    const int c0 = (int)blockIdx.x * cpb;
    const int c1 = (c0 + cpb < nch) ? (c0 + cpb) : nch;
    if (c0 >= c1) return;                     // whole block (before any sync)

    // ---- stage all 16 systems' W (f32 -> bf16 RN, packed pairs) + b ----
    const float2* __restrict__ Wg = (const float2*)W;   // pair (d, d+1)
    for (int u = tid; u < S_SYS * (C_CLS * D_DIM / 2); u += BLK) {
        const int s = u / (C_CLS * D_DIM / 2);          // 1280 pairs per system
        const int w = u - s * (C_CLS * D_DIM / 2);
        const float2 f = Wg[u];
        unsigned lo = __float_as_uint(f.x);
        unsigned hi = __float_as_uint(f.y);
        lo = (lo + 0x7FFFu + ((lo >> 16) & 1u)) >> 16;  // RN-even bf16
        hi = (hi + 0x7FFFu + ((hi >> 16) & 1u)) >> 16;
        Wl[s * WSTR + w] = (hi << 16) | lo;
    }
    if (tid < S_SYS * C_CLS) bl[tid] = b[tid];
    __syncthreads();

    const int g = tid >> 3;                   // group (0..127) = sample within chunk
    const int q = tid & 7;                    // lane within group

    // ---- 2-deep software pipeline over this block's contiguous chunk span ----
    float4 A[8], Bf[8];
    int ch = c0;
    long iA = (long)ch * CPB + g;
    load_x(A, x, iA, n, q);
    while (true) {
        const int chB = ch + 1;
        const bool vB = (chB < c1);
        const long iB = (long)chB * CPB + g;
        if (vB) load_x(Bf, x, iB, n, q);
        step_compute(A, iA, n, q, Wl, bl, sid, out);
        if (!vB) break;

        const int chA = chB + 1;
        const bool vA = (chA < c1);
        const long iA2 = (long)chA * CPB + g;
        if (vA) load_x(A, x, iA2, n, q);
        step_compute(Bf, iB, n, q, Wl, bl, sid, out);
        if (!vA) break;
        ch = chA; iA = iA2;
    }
}

extern "C" void kernel_launch(void* const* d_in, const int* in_sizes, int n_in,
                              void* d_out, int out_size, void* d_ws, size_t ws_size,
                              hipStream_t stream) {
    const float* x = (const float*)d_in[0];
    const int* sid = (const int*)d_in[1];
    const float* W = (const float*)d_in[2];
    const float* b = (const float*)d_in[3];
    float* out = (float*)d_out;
    const int n = in_sizes[1];   // B

    mainf_k<<<GRID, BLK, 0, stream>>>(x, sid, W, b, out, n);
}

// Round 9
// 59.018 us; speedup vs baseline: 12.9268x; 1.1790x over previous
//
#include <hip/hip_runtime.h>
#include <hip/hip_bf16.h>

// Problem constants (from reference): B=262144, D=256, S=16, C=10.
#define D_DIM 256
#define S_SYS 16
#define C_CLS 10
#define BLK   1024                 // 16 waves/block, 1 block/CU (LDS-capped)
#define GRID  256
#define CPB   128                  // samples per chunk (1024 threads / 8 lanes-per-sample)

// LDS W layout: u32 = 2 packed bf16 (dims d, d+1).
//   slot(s, c, q, v) = s*S_STR + c*C_STR + q*L_STR + v      (v = 0..15 real, 16..19 pad)
//   v = 2j + t  ->  weight u32 for dims  j*32 + q*4 + 2t .. +1
// Per-lane, per-class: 16 CONTIGUOUS u32 -> 4x ds_read_b128.
// Banks: lane q starts at (20q mod 32) = {0,20,8,28,16,4,24,12} -> 8 lanes x 4 banks
// cover all 32 banks exactly once per instruction -> conflict-free within a group.
// S_STR mod 32 = 4 -> per-system bank rotation keeps mixed-sid waves uniform.
#define L_STR 20
#define C_STR 160      // 8 * L_STR
#define S_STR 1604     // C_CLS * C_STR + 4

__device__ __forceinline__ void load_x(float4 xb[8], const float* __restrict__ x,
                                       long i, int n, int q) {
    const long r = (i < n) ? i : (long)(n - 1);           // clamp (store is masked)
    const float4* p = (const float4*)(x + r * D_DIM) + q; // dims j*32 + q*4 .. +3
    #pragma unroll
    for (int j = 0; j < 8; ++j) xb[j] = p[j * 8];
}

__device__ __forceinline__ int load_sid(const int* __restrict__ sid, long i, int n) {
    return sid[(i < n) ? i : (long)(n - 1)] & (S_SYS - 1);
}

__device__ __forceinline__ void step_compute(const float4 xb[8], long i, int n, int q, int s,
                                             const unsigned* __restrict__ Wl,
                                             const float* __restrict__ bl,
                                             float* __restrict__ out) {
    const unsigned* wp = Wl + (unsigned)s * S_STR + (unsigned)q * L_STR;

    float acc[C_CLS];
    #pragma unroll
    for (int c = 0; c < C_CLS; ++c) {
        float a = 0.f;
        #pragma unroll
        for (int k = 0; k < 4; ++k) {                     // quad k covers j = 2k, 2k+1
            const uint4 wv = *(const uint4*)&wp[c * C_STR + 4 * k];
            const float4 x0 = xb[2 * k];
            const float4 x1 = xb[2 * k + 1];
            a = fmaf(x0.x, __uint_as_float(wv.x << 16),
                 fmaf(x0.y, __uint_as_float(wv.x & 0xFFFF0000u),
                  fmaf(x0.z, __uint_as_float(wv.y << 16),
                   fmaf(x0.w, __uint_as_float(wv.y & 0xFFFF0000u),
                    fmaf(x1.x, __uint_as_float(wv.z << 16),
                     fmaf(x1.y, __uint_as_float(wv.z & 0xFFFF0000u),
                      fmaf(x1.z, __uint_as_float(wv.w << 16),
                       fmaf(x1.w, __uint_as_float(wv.w & 0xFFFF0000u), a))))))));
        }
        acc[c] = a;
    }

    // all-reduce each class within the 8-lane group (xor 1,2,4 stay in-group)
    float v0 = 0.f, v1 = 0.f;
    #pragma unroll
    for (int c = 0; c < C_CLS; ++c) {
        float r = acc[c];
        r += __shfl_xor(r, 1);
        r += __shfl_xor(r, 2);
        r += __shfl_xor(r, 4);
        if (c == q)     v0 = r;   // compile-time c, runtime compare (no scratch)
        if (c == 8 + q) v1 = r;
    }
    if (i < n) {
        float* op = out + i * C_CLS;
        op[q] = v0 + bl[s * C_CLS + q];
        if (q < 2) op[8 + q] = v1 + bl[s * C_CLS + 8 + q];
    }
}

__global__ __launch_bounds__(BLK) void mainf_k(const float* __restrict__ x,
                                               const int* __restrict__ sid,
                                               const float* __restrict__ W,
                                               const float* __restrict__ b,
                                               float* __restrict__ out, int n) {
    __shared__ unsigned Wl[S_SYS * S_STR];    // 102,656 B
    __shared__ float    bl[S_SYS * C_CLS];    // 640 B

    const int tid = threadIdx.x;
    const int nch = (n + CPB - 1) / CPB;
    const int cpb = (nch + (int)gridDim.x - 1) / (int)gridDim.x;  // chunks per block
    const int c0 = (int)blockIdx.x * cpb;
    const int c1 = (c0 + cpb < nch) ? (c0 + cpb) : nch;
    if (c0 >= c1) return;                     // whole block exits (before any sync)

    // ---- stage all 16 systems' W (f32 -> bf16 RN-even, packed pairs), permuted ----
    const float2* __restrict__ Wg = (const float2*)W;   // pair-index: sc*128 + j*16 + q*2 + t
    for (int u = tid; u < S_SYS * C_CLS * 8 * 16; u += BLK) {   // 20480 real slots
        const int v  = u & 15;
        const int q  = (u >> 4) & 7;
        const int sc = u >> 7;                 // s*10 + c
        const int j  = v >> 1, t = v & 1;
        const float2 f = Wg[(size_t)sc * 128 + j * 16 + q * 2 + t];
        unsigned lo = __float_as_uint(f.x);
        unsigned hi = __float_as_uint(f.y);
        lo = (lo + 0x7FFFu + ((lo >> 16) & 1u)) >> 16;  // RN-even bf16
        hi = (hi + 0x7FFFu + ((hi >> 16) & 1u)) >> 16;
        const int s = sc / C_CLS, c = sc - s * C_CLS;
        Wl[s * S_STR + c * C_STR + q * L_STR + v] = (hi << 16) | lo;
    }
    if (tid < S_SYS * C_CLS) bl[tid] = b[tid];
    __syncthreads();

    const int g = tid >> 3;                   // group (0..127) = sample within chunk
    const int q = tid & 7;                    // lane within group

    // ---- 2-deep pipeline; sid prefetched WITH x (keeps vmcnt queue pure-prefetch) ----
    float4 A[8], Bf[8];
    int ch = c0;
    long iA = (long)ch * CPB + g;
    load_x(A, x, iA, n, q);
    int sA = load_sid(sid, iA, n);
    while (true) {
        const int chB = ch + 1;
        const bool vB = (chB < c1);
        const long iB = (long)chB * CPB + g;
        int sB = 0;
        if (vB) { load_x(Bf, x, iB, n, q); sB = load_sid(sid, iB, n); }
        step_compute(A, iA, n, q, sA, Wl, bl, out);
        if (!vB) break;

        const int chA2 = chB + 1;
        const bool vA = (chA2 < c1);
        const long iA2 = (long)chA2 * CPB + g;
        if (vA) { load_x(A, x, iA2, n, q); sA = load_sid(sid, iA2, n); }
        step_compute(Bf, iB, n, q, sB, Wl, bl, out);
        if (!vA) break;
        ch = chA2; iA = iA2;
    }
}

extern "C" void kernel_launch(void* const* d_in, const int* in_sizes, int n_in,
                              void* d_out, int out_size, void* d_ws, size_t ws_size,
                              hipStream_t stream) {
    const float* x = (const float*)d_in[0];
    const int* sid = (const int*)d_in[1];
    const float* W = (const float*)d_in[2];
    const float* b = (const float*)d_in[3];
    float* out = (float*)d_out;
    const int n = in_sizes[1];   // B

    mainf_k<<<GRID, BLK, 0, stream>>>(x, sid, W, b, out, n);
}